// Round 7
// baseline (186.404 us; speedup 1.0000x reference)
//
#include <hip/hip_runtime.h>

#define N_NODES 50000
#define E_EDGES 800000
#define CIN     32
#define COUT    64
#define NB      16       // cell buckets
#define BCAP    54016    // per-bucket rec capacity (16-aligned; avg 50000 +18s)
#define NCB     196      // coarse row buckets (row>>8)
#define RCAP    4864     // per-coarse-bucket capacity (avg 4082 +12s)
#define EPB     2        // edges per thread in build_recs (was 8: 391 blocks =
                         // 1.5 blocks/CU, serialization-bound; 2 -> 1563 blocks)
#define BBLK    ((E_EDGES + EPB * 256 - 1) / (EPB * 256))   // 1563 blocks
#define XCHUNK  (N_NODES * CIN / 4)                // 400000 f4 chunks
#define KPAD    136      // fallback-path LDS row stride (shorts)

typedef __attribute__((ext_vector_type(8))) short s8v;   // 8 bf16 = 4 VGPRs
typedef __attribute__((ext_vector_type(4))) float f4v;
typedef __attribute__((ext_vector_type(4))) unsigned short u4v;

static __device__ inline unsigned short f2bf(float f) {  // RTNE via v_cvt_pk_bf16_f32
    __bf16 b = (__bf16)f;
    return __builtin_bit_cast(unsigned short, b);
}
static __device__ inline float bf2f(unsigned short h) {
    unsigned u = ((unsigned)h) << 16;
    return __builtin_bit_cast(float, u);
}
static __device__ inline unsigned f2bf2(float a, float b) {
    return (unsigned)f2bf(a) | ((unsigned)f2bf(b) << 16);
}

// ============ main path: zero scattered global atomics ============

// fused: x->bf16 slice + cell-bucketed recs + row-coarse (row,recslot) pairs.
// rec = row:16|col:16|f0q:16|f1q:16.  rp entry = recslot:20|rowlow:8.
__global__ __launch_bounds__(256) void build_recs(
    const float* __restrict__ x, unsigned short* __restrict__ xbf,
    const int* __restrict__ ei, const float* __restrict__ pseudo,
    int* __restrict__ cursor, int* __restrict__ cursR,
    unsigned long long* __restrict__ recs, unsigned* __restrict__ rp)
{
    // x2bf slice: 1563 blocks x 256 chunks covers 400128 >= 400000
    {
        const int i = blockIdx.x * 256 + threadIdx.x;
        if (i < XCHUNK) {
            f4v v = *(const f4v*)(x + (size_t)i * 4);
            union { unsigned u2[2]; u4v v4; } o;
            o.u2[0] = f2bf2(v[0], v[1]);
            o.u2[1] = f2bf2(v[2], v[3]);
            *(u4v*)(xbf + (size_t)i * 4) = o.v4;
        }
    }

    __shared__ int lh[NB];
    __shared__ int lbase[NB];
    __shared__ int lh2[NCB];
    __shared__ int lbase2[NCB];
    if (threadIdx.x < NB) lh[threadIdx.x] = 0;
    if (threadIdx.x < NCB) lh2[threadIdx.x] = 0;
    __syncthreads();

    const int ebase0 = blockIdx.x * (EPB * 256);
    unsigned long long rcache[EPB];
    int pcache[EPB];    // b | myoff<<8
    int pcache2[EPB];   // cb | myoff2<<8

#pragma unroll
    for (int i = 0; i < EPB; ++i) {
        const int e = ebase0 + i * 256 + threadIdx.x;
        pcache[i] = -1; pcache2[i] = -1;
        if (e < E_EDGES) {
            const int row = min(max(ei[e], 0), N_NODES - 1);
            const int col = min(max(ei[E_EDGES + e], 0), N_NODES - 1);
            const float v0 = pseudo[2 * e] * 4.0f, v1 = pseudo[2 * e + 1] * 4.0f;
            const float fl0 = floorf(v0), fl1 = floorf(v1);
            const int lo0 = min(max((int)fl0, 0), 3);
            const int lo1 = min(max((int)fl1, 0), 3);
            const int f0q = min((int)((v0 - fl0) * 65536.0f), 65535);
            const int f1q = min((int)((v1 - fl1) * 65536.0f), 65535);
            const int b = lo0 + 4 * lo1;
            rcache[i] = (unsigned long long)row
                      | ((unsigned long long)col << 16)
                      | ((unsigned long long)f0q << 32)
                      | ((unsigned long long)f1q << 48);
            pcache[i]  = b | (atomicAdd(&lh[b], 1) << 8);
            const int cb = row >> 8;
            pcache2[i] = cb | (atomicAdd(&lh2[cb], 1) << 8);
        }
    }
    __syncthreads();

    if (threadIdx.x < NB)
        lbase[threadIdx.x] = atomicAdd(&cursor[threadIdx.x], lh[threadIdx.x]);
    if (threadIdx.x < NCB)
        lbase2[threadIdx.x] = atomicAdd(&cursR[threadIdx.x], lh2[threadIdx.x]);
    __syncthreads();

#pragma unroll
    for (int i = 0; i < EPB; ++i) {
        if (pcache[i] >= 0) {
            const int b = pcache[i] & 0xFF;
            const int idx = min(lbase[b] + (pcache[i] >> 8), BCAP - 1);
            const unsigned recslot = (unsigned)(b * BCAP + idx);
            recs[recslot] = rcache[i];
            const int cb = pcache2[i] & 0xFF;
            const int idx2 = min(lbase2[cb] + (pcache2[i] >> 8), RCAP - 1);
            const unsigned rowlow = (unsigned)(rcache[i] & 0xFF);
            rp[(size_t)cb * RCAP + idx2] = recslot | (rowlow << 20);
        }
    }
}

// fused per-coarse-bucket: self-compute 196-entry bstart prefix (tiny, L2),
// load rp bucket to LDS once, 256-bin hist, in-block exclusive scan ->
// rowstart, then rank-assign -> dpos.  (scanR_k dispatch folded in)
__global__ __launch_bounds__(256) void bucket_rank(
    const unsigned* __restrict__ rp, const int* __restrict__ cursR,
    int* __restrict__ rowstart, int* __restrict__ dpos)
{
    __shared__ unsigned ent[RCAP];
    __shared__ int h[256];
    __shared__ int ws[4];
    __shared__ int wo[4];
    __shared__ int cur[256];
    __shared__ int sbase;
    const int cb = blockIdx.x, tid = threadIdx.x;
    const int lane = tid & 63, wid = tid >> 6;
    h[tid] = 0;

    // scan 1: exclusive prefix over the 196 coarse-bucket counts
    {
        const int v = (tid < NCB) ? min(cursR[tid], RCAP) : 0;
        int val = v;
#pragma unroll
        for (int off = 1; off < 64; off <<= 1) {
            int t = __shfl_up(val, off);
            if (lane >= off) val += t;
        }
        if (lane == 63) ws[wid] = val;
        __syncthreads();
        if (tid == 0) {
            int a = 0;
#pragma unroll
            for (int w = 0; w < 4; ++w) { wo[w] = a; a += ws[w]; }
        }
        __syncthreads();
        if (tid == cb) sbase = wo[wid] + val - v;      // this block's base
        if (cb == 0 && tid == 0) rowstart[N_NODES] = wo[3] + ws[3];
    }
    __syncthreads();   // sbase visible; h zero-init covered; wo/ws consumed

    const int cnt = min(cursR[cb], RCAP);
    const unsigned* bp = rp + (size_t)cb * RCAP;
    for (int i = tid; i < cnt; i += 256) {
        const unsigned e = bp[i];
        ent[i] = e;
        atomicAdd(&h[e >> 20], 1);
    }
    __syncthreads();

    // scan 2: exclusive scan of h[256] (ws/wo safely reused)
    const int v = h[tid];
    int val = v;
#pragma unroll
    for (int off = 1; off < 64; off <<= 1) {
        int t = __shfl_up(val, off);
        if (lane >= off) val += t;
    }
    if (lane == 63) ws[wid] = val;
    __syncthreads();
    if (tid == 0) {
        int a = 0;
#pragma unroll
        for (int w = 0; w < 4; ++w) { wo[w] = a; a += ws[w]; }
    }
    __syncthreads();

    const int rs = sbase + wo[wid] + (val - v);
    const int row = cb * 256 + tid;
    if (row < N_NODES) rowstart[row] = rs;
    cur[tid] = rs;
    __syncthreads();

    for (int i = tid; i < cnt; i += 256) {
        const unsigned e = ent[i];
        const int pos = min(atomicAdd(&cur[e >> 20], 1), E_EDGES - 1);
        dpos[e & 0xFFFFF] = pos;
    }
}

// pass D: per-cell MFMA, pipelined; msg SCATTER-stored at row-sorted pos.
// LDS chunk-rotated (bank-conflict-free); 1/deg folded into the gather.
// !! LAUNCH CONFIG IS CORRECTNESS-SENSITIVE (empirical, R3+R4 failures):
// !!   (256,4) + grid 16*256  -> FAILS (absmax 0.024 clean / 468 poisoned)
// !!   (256,2) + grid 16*128  -> PASSES (R2, 173.1us). Do not bump without
// !!   a hardened-barrier variant; suspect codegen at the 128-VGPR cap
// !!   interacting with the wave_barrier-only pipeline.
__global__ __launch_bounds__(256, 2) void bucket_mfma_seq(
    const unsigned short* __restrict__ xbf, const float* __restrict__ weight,
    const unsigned long long* __restrict__ recs,
    const int* __restrict__ cursor,
    const int* __restrict__ dpos, unsigned short* __restrict__ msg)
{
    __shared__ short XS[4][2048];   // 4KB/wave: staging 16 rows x 256B (rot16)

    const int lane = threadIdx.x & 63;
    const int wid  = threadIdx.x >> 6;
    const int cell = blockIdx.x & (NB - 1);
    const int wGlob   = (blockIdx.x >> 4) * 4 + wid;
    const int wStride = (gridDim.x >> 4) * 4;
    const int eg = lane >> 2, part = lane & 3;

    const int lo0 = cell & 3, lo1 = cell >> 2;
    const int base = lo0 + 5 * lo1;
    const int offs[4] = {0, 1, 5, 6};
    const int q = lane >> 4;
    const int c = lane & 15;

    s8v bfr[4][4];
#pragma unroll
    for (int s = 0; s < 4; ++s) {
        const float* wp = weight + (size_t)(base + offs[s]) * (CIN * COUT);
#pragma unroll
        for (int nt = 0; nt < 4; ++nt) {
            union { unsigned short u[8]; s8v v; } tmp;
#pragma unroll
            for (int j = 0; j < 8; ++j)
                tmp.u[j] = f2bf(wp[(q * 8 + j) * COUT + nt * 16 + c]);
            bfr[s][nt] = tmp.v;
        }
    }

    // loop-invariant rotated LDS addresses (shorts)
    short* const swrow = &XS[wid][eg * 128];           // staging write row
    int swoff[4];                                      // chunk (4s+part+eg)&15
#pragma unroll
    for (int s = 0; s < 4; ++s) swoff[s] = ((4 * s + part + eg) & 15) * 8;
    const short* const arrow = &XS[wid][c * 128];      // A-read row
    int aroff[4];                                      // chunk (4ks+q+c)&15
#pragma unroll
    for (int ks = 0; ks < 4; ++ks) aroff[ks] = ((4 * ks + q + c) & 15) * 8;
    // epilogue (rows of 128B = 8 chunks, rot8)
    const int erlo = eg * 64 + ((part + eg) & 7) * 8;        // read vlo
    const int erhi = eg * 64 + ((part + 4 + eg) & 7) * 8;    // read vhi

    const unsigned long long* brec = recs + (size_t)cell * BCAP;
    const int* bdp = dpos + (size_t)cell * BCAP;
    const int cnt    = min(cursor[cell], BCAP);
    const int ntiles = (cnt + 15) >> 4;

    int t = wGlob;
    unsigned long long rec_c = 0;
    int dp_c  = 0;
    s8v x_c = {};
    if (t < ntiles) {
        const int ri = min(t * 16 + eg, cnt - 1);
        rec_c = brec[ri];
        dp_c  = bdp[ri];
        x_c = *(const s8v*)(xbf + (size_t)((rec_c >> 16) & 0xFFFF) * CIN + part * 8);
    }

    for (; t < ntiles; t += wStride) {
        const int tn = t + wStride;
        unsigned long long rec_n = 0;
        int dp_n  = 0;
        if (tn < ntiles) {
            const int ri = min(tn * 16 + eg, cnt - 1);
            rec_n = brec[ri];
            dp_n  = bdp[ri];
        }

        const bool vcur = (t * 16 + eg) < cnt;
        const float f0 = (float)(int)((rec_c >> 32) & 0xFFFF) * (1.0f / 65536.0f);
        const float f1 = (float)(int)((rec_c >> 48) & 0xFFFF) * (1.0f / 65536.0f);
        const float s0 = (1.0f - f0) * (1.0f - f1);
        const float s1 = f0 * (1.0f - f1);
        const float s2 = (1.0f - f0) * f1;
        const float s3 = f0 * f1;

        // stage scaled X' (16 x 128 bf16), chunk-rotated
        {
            union { unsigned short u[8]; s8v v; } xin; xin.v = x_c;
            float xv[8];
#pragma unroll
            for (int j = 0; j < 8; ++j) xv[j] = bf2f(xin.u[j]);
            const float ss[4] = {s0, s1, s2, s3};
#pragma unroll
            for (int s = 0; s < 4; ++s) {
                union { unsigned u2[4]; s8v v; } tmp;
#pragma unroll
                for (int j = 0; j < 8; j += 2)
                    tmp.u2[j >> 1] = f2bf2(ss[s] * xv[j], ss[s] * xv[j + 1]);
                *(s8v*)(swrow + swoff[s]) = tmp.v;
            }
        }
        __builtin_amdgcn_wave_barrier();

        s8v afr[4];
#pragma unroll
        for (int ks = 0; ks < 4; ++ks)
            afr[ks] = *(const s8v*)(arrow + aroff[ks]);
        __builtin_amdgcn_wave_barrier();

        // next tile's x gather overlaps MFMA + epilogue
        s8v x_n = {};
        if (tn < ntiles)
            x_n = *(const s8v*)(xbf + (size_t)((rec_n >> 16) & 0xFFFF) * CIN + part * 8);

        f4v acc[4];
#pragma unroll
        for (int nt = 0; nt < 4; ++nt) {
            acc[nt] = (f4v){0.f, 0.f, 0.f, 0.f};
#pragma unroll
            for (int ks = 0; ks < 4; ++ks)
                acc[nt] = __builtin_amdgcn_mfma_f32_16x16x32_bf16(
                    afr[ks], bfr[ks][nt], acc[nt], 0, 0, 0);
        }

        // epilogue: acc -> bf16 tile in LDS (rot8) -> 128B scatter store at dp_c
#pragma unroll
        for (int r = 0; r < 4; ++r) {
            const int m = q * 4 + r;
#pragma unroll
            for (int nt = 0; nt < 4; ++nt) {
                const int chunk = (2 * nt + (c >> 3) + m) & 7;
                XS[wid][m * 64 + chunk * 8 + (c & 7)] = (short)f2bf(acc[nt][r]);
            }
        }
        __builtin_amdgcn_wave_barrier();
        if (vcur) {
            s8v vlo = *(const s8v*)&XS[wid][erlo];
            s8v vhi = *(const s8v*)&XS[wid][erhi];
            unsigned short* dst = msg + (size_t)dp_c * COUT + part * 8;
            *(s8v*)dst = vlo;
            *(s8v*)(dst + 32) = vhi;
        }
        __builtin_amdgcn_wave_barrier();

        rec_c = rec_n; dp_c = dp_n; x_c = x_n;
    }
}

// pass E: SEQUENTIAL per-node segment sum (msg already row-sorted) +
// 1/deg (deg == segment length) + root/bias fuse.
__global__ __launch_bounds__(256) void gather_seq(
    const unsigned short* __restrict__ msg,
    const int* __restrict__ rowstart, const float* __restrict__ x,
    const float* __restrict__ root, const float* __restrict__ bias,
    float* __restrict__ out)
{
    const int wave   = (blockIdx.x * blockDim.x + threadIdx.x) >> 6;
    const int lane   = threadIdx.x & 63;
    const int nwaves = (gridDim.x * blockDim.x) >> 6;
    const int g = lane >> 3;   // 0..7: position group / root i-range
    const int c = lane & 7;    // channel octet: channels c*8 .. c*8+7

    // hoist root fragment (this lane's 4 rows x 8 channels) + bias
    float rfr[4][8];
#pragma unroll
    for (int i = 0; i < 4; ++i) {
        const int ii = g * 4 + i;
        *(f4v*)&rfr[i][0] = *(const f4v*)(root + (size_t)ii * COUT + c * 8);
        *(f4v*)&rfr[i][4] = *(const f4v*)(root + (size_t)ii * COUT + c * 8 + 4);
    }
    float bs[8];
    *(f4v*)&bs[0] = *(const f4v*)(bias + c * 8);
    *(f4v*)&bs[4] = *(const f4v*)(bias + c * 8 + 4);

    for (int n = wave; n < N_NODES; n += nwaves) {
        const int s  = rowstart[n];
        const int e2 = rowstart[n + 1];
        float acc[8] = {0.f, 0.f, 0.f, 0.f, 0.f, 0.f, 0.f, 0.f};

        // streaming segment sum: 8 positions x 64 ch per wave iteration
        for (int p = s + g; p < e2; p += 8) {
            union { s8v v; unsigned short u[8]; } mv;
            mv.v = *(const s8v*)(msg + (size_t)p * COUT + c * 8);
#pragma unroll
            for (int j = 0; j < 8; ++j)
                acc[j] += bf2f(mv.u[j]);
        }

        // 1/deg scaling (deg == segment length; applied before root partial)
        const float invd = 1.0f / (float)max(e2 - s, 1);
#pragma unroll
        for (int j = 0; j < 8; ++j) acc[j] *= invd;

        // root partial: this group's 4 input channels
        const f4v xv4 = *(const f4v*)(x + (size_t)n * CIN + g * 4);
#pragma unroll
        for (int i = 0; i < 4; ++i) {
            const float xv = xv4[i];
#pragma unroll
            for (int j = 0; j < 8; ++j)
                acc[j] += xv * rfr[i][j];
        }

        // reduce across the 8 groups
#pragma unroll
        for (int off = 8; off < 64; off <<= 1) {
#pragma unroll
            for (int j = 0; j < 8; ++j)
                acc[j] += __shfl_xor(acc[j], off);
        }

        if (g == 0) {
            f4v o0, o1;
#pragma unroll
            for (int j = 0; j < 4; ++j) o0[j] = acc[j] + bs[j];
#pragma unroll
            for (int j = 0; j < 4; ++j) o1[j] = acc[4 + j] + bs[4 + j];
            float* op = out + (size_t)n * COUT + c * 8;
            *(f4v*)op = o0;
            *(f4v*)(op + 4) = o1;
        }
    }
}

// ================= fallback (R4 atomic) path =================

__global__ __launch_bounds__(256) void count_fb(
    const int* __restrict__ ei, const float* __restrict__ pseudo,
    int* __restrict__ hist, float* __restrict__ deg)
{
    __shared__ int lh[16];
    if (threadIdx.x < 16) lh[threadIdx.x] = 0;
    __syncthreads();
    const int e = blockIdx.x * 256 + threadIdx.x;
    if (e < E_EDGES) {
        int row = min(max(ei[e], 0), N_NODES - 1);
        const float v0 = pseudo[2 * e] * 4.0f, v1 = pseudo[2 * e + 1] * 4.0f;
        const int lo0 = min(max((int)floorf(v0), 0), 3);
        const int lo1 = min(max((int)floorf(v1), 0), 3);
        atomicAdd(&lh[lo0 + 4 * lo1], 1);
        atomicAdd(&deg[row], 1.0f);
    }
    __syncthreads();
    if (threadIdx.x < 16) atomicAdd(&hist[threadIdx.x], lh[threadIdx.x]);
}

__global__ void scan16_fb(const int* __restrict__ hist,
                          int* __restrict__ bstart, int* __restrict__ cursor)
{
    if (threadIdx.x == 0 && blockIdx.x == 0) {
        int acc = 0;
        for (int c = 0; c < 16; ++c) { bstart[c] = acc; cursor[c] = acc; acc += hist[c]; }
    }
}

__global__ __launch_bounds__(256) void scatter_fb(
    const float* __restrict__ pseudo, int* __restrict__ cursor, int* __restrict__ list)
{
    __shared__ int lh[16];
    __shared__ int lbase[16];
    if (threadIdx.x < 16) lh[threadIdx.x] = 0;
    __syncthreads();
    const int e = blockIdx.x * 256 + threadIdx.x;
    int cell = 0, myoff = 0;
    if (e < E_EDGES) {
        const float v0 = pseudo[2 * e] * 4.0f, v1 = pseudo[2 * e + 1] * 4.0f;
        const int lo0 = min(max((int)floorf(v0), 0), 3);
        const int lo1 = min(max((int)floorf(v1), 0), 3);
        cell = lo0 + 4 * lo1;
        myoff = atomicAdd(&lh[cell], 1);
    }
    __syncthreads();
    if (threadIdx.x < 16)
        lbase[threadIdx.x] = atomicAdd(&cursor[threadIdx.x], lh[threadIdx.x]);
    __syncthreads();
    if (e < E_EDGES)
        list[lbase[cell] + myoff] = e;
}

__global__ __launch_bounds__(256, 2) void bucket_mfma_fb(
    const float* __restrict__ x, const int* __restrict__ ei,
    const float* __restrict__ pseudo, const float* __restrict__ weight,
    const int* __restrict__ list, const int* __restrict__ bstart,
    const int* __restrict__ hist, float* __restrict__ out)
{
    __shared__ short XS[4][16 * KPAD];
    const int lane = threadIdx.x & 63;
    const int wid  = threadIdx.x >> 6;
    const int beta = blockIdx.x & 15;
    const int wGlob   = (blockIdx.x >> 4) * 4 + wid;
    const int wStride = (gridDim.x >> 4) * 4;
    const int lo0 = beta & 3, lo1 = beta >> 2;
    const int base = lo0 + 5 * lo1;
    const int offs[4] = {0, 1, 5, 6};
    const int q = lane >> 4, c = lane & 15;

    s8v bfr[4][4];
#pragma unroll
    for (int s = 0; s < 4; ++s) {
        const float* wp = weight + (size_t)(base + offs[s]) * (CIN * COUT);
#pragma unroll
        for (int nt = 0; nt < 4; ++nt) {
            union { unsigned short u[8]; s8v v; } tmp;
#pragma unroll
            for (int j = 0; j < 8; ++j)
                tmp.u[j] = f2bf(wp[(q * 8 + j) * COUT + nt * 16 + c]);
            bfr[s][nt] = tmp.v;
        }
    }
    const int start = bstart[beta], cnt = hist[beta];
    const int ntiles = (cnt + 15) >> 4;

    for (int t = wGlob; t < ntiles; t += wStride) {
        const int ebase = start + t * 16;
        int rowv = 0, colv = 0;
        float b0 = 0.f, b1 = 0.f, b2 = 0.f, b3 = 0.f;
        if (lane < 16 && (t * 16 + lane) < cnt) {
            const int e = list[ebase + lane];
            rowv = min(max(ei[e], 0), N_NODES - 1);
            colv = min(max(ei[E_EDGES + e], 0), N_NODES - 1);
            const float v0 = pseudo[2 * e] * 4.0f, v1 = pseudo[2 * e + 1] * 4.0f;
            const float f0 = v0 - floorf(v0), f1 = v1 - floorf(v1);
            b0 = (1.0f - f0) * (1.0f - f1);
            b1 = f0 * (1.0f - f1);
            b2 = (1.0f - f0) * f1;
            b3 = f0 * f1;
        }
        {
            const int eg = lane >> 2, part = lane & 3;
            const int  gc = __shfl(colv, eg);
            const float ss0 = __shfl(b0, eg), ss1 = __shfl(b1, eg);
            const float ss2 = __shfl(b2, eg), ss3 = __shfl(b3, eg);
            const float ss[4] = {ss0, ss1, ss2, ss3};
            const float* xp = x + (size_t)gc * CIN + part * 8;
            float xv[8];
            *(f4v*)&xv[0] = *(const f4v*)xp;
            *(f4v*)&xv[4] = *(const f4v*)(xp + 4);
            short* dst = &XS[wid][eg * KPAD + part * 8];
#pragma unroll
            for (int s = 0; s < 4; ++s) {
                union { unsigned short u[8]; s8v v; } tmp;
#pragma unroll
                for (int j = 0; j < 8; ++j)
                    tmp.u[j] = f2bf(ss[s] * xv[j]);
                *(s8v*)(dst + s * 32) = tmp.v;
            }
        }
        __builtin_amdgcn_wave_barrier();
        s8v afr[4];
        {
            const short* ap = &XS[wid][c * KPAD + q * 8];
#pragma unroll
            for (int ks = 0; ks < 4; ++ks)
                afr[ks] = *(const s8v*)(ap + ks * 32);
        }
        __builtin_amdgcn_wave_barrier();
        f4v acc[4];
#pragma unroll
        for (int nt = 0; nt < 4; ++nt) {
            acc[nt] = (f4v){0.f, 0.f, 0.f, 0.f};
#pragma unroll
            for (int ks = 0; ks < 4; ++ks)
                acc[nt] = __builtin_amdgcn_mfma_f32_16x16x32_bf16(
                    afr[ks], bfr[ks][nt], acc[nt], 0, 0, 0);
        }
#pragma unroll
        for (int r = 0; r < 4; ++r) {
            const int m = q * 4 + r;
            const int orow = __shfl(rowv, m);
#pragma unroll
            for (int nt = 0; nt < 4; ++nt)
                atomicAdd(&out[(size_t)orow * COUT + nt * 16 + c], acc[nt][r]);
        }
    }
}

__global__ __launch_bounds__(256) void final_fb(
    const float* __restrict__ x, const float* __restrict__ root,
    const float* __restrict__ bias, const float* __restrict__ deg,
    float* __restrict__ out)
{
    const int wave   = (blockIdx.x * blockDim.x + threadIdx.x) >> 6;
    const int lane   = threadIdx.x & 63;
    const int nwaves = (gridDim.x * blockDim.x) >> 6;
    for (int n = wave; n < N_NODES; n += nwaves) {
        const float* xp = x + (size_t)n * CIN;
        float acc = bias[lane];
#pragma unroll
        for (int i = 0; i < CIN; ++i)
            acc += xp[i] * root[i * COUT + lane];
        float dg = deg[n];
        dg = dg > 1.0f ? dg : 1.0f;
        const size_t idx = (size_t)n * COUT + lane;
        out[idx] = out[idx] / dg + acc;
    }
}

extern "C" void kernel_launch(void* const* d_in, const int* in_sizes, int n_in,
                              void* d_out, int out_size, void* d_ws, size_t ws_size,
                              hipStream_t stream) {
    const float* x      = (const float*)d_in[0];
    const int*   ei     = (const int*)d_in[1];
    const float* pseudo = (const float*)d_in[2];
    const float* weight = (const float*)d_in[3];
    const float* root   = (const float*)d_in[4];
    const float* bias   = (const float*)d_in[5];
    float* out = (float*)d_out;

    // ws layout (int elements)
    int* wsI = (int*)d_ws;
    int* cursor16 = wsI;                         // 16 (+16 pad)
    int* cursR    = wsI + 32;                    // 196 (+28 pad) -> 224
    int* rowstart = wsI + 50256;                 // 50001 (+15 pad)
    // byte offsets from 100352*4 = 401408 (layout kept from prev rounds)
    unsigned long long* recs = (unsigned long long*)((char*)d_ws + 401408);        // 6.91 MB
    unsigned* rp   = (unsigned*)((char*)recs + (size_t)NB * BCAP * 8);             // 3.81 MB
    int* dpos      = (int*)((char*)rp + (size_t)NCB * RCAP * 4);                   // 3.46 MB
    unsigned short* xbf = (unsigned short*)((char*)dpos + (size_t)NB * BCAP * 4);  // 3.2 MB
    unsigned short* msg = (unsigned short*)((char*)xbf + (size_t)N_NODES * CIN * 2); // 102.4 MB
    const size_t needed = 401408 + (size_t)NB * BCAP * 8 + (size_t)NCB * RCAP * 4
                        + (size_t)NB * BCAP * 4 + (size_t)N_NODES * CIN * 2
                        + (size_t)E_EDGES * COUT * 2;   // ~120.2 MB

    if (ws_size >= needed) {
        (void)hipMemsetAsync(d_ws, 0, 256 * 4, stream);   // cursor16 + cursR only
        build_recs <<<BBLK, 256, 0, stream>>>(x, xbf, ei, pseudo, cursor16, cursR, recs, rp);
        bucket_rank<<<NCB, 256, 0, stream>>>(rp, cursR, rowstart, dpos);
        bucket_mfma_seq<<<16 * 128, 256, 0, stream>>>(
            xbf, weight, recs, cursor16, dpos, msg);
        gather_seq<<<4096, 256, 0, stream>>>(msg, rowstart, x, root, bias, out);
    } else {
        // R4 fallback layout
        char* w = (char*)d_ws;
        float* degF   = (float*)w;
        int*   histF  = (int*)(w + 200064);
        int*   bstF   = (int*)(w + 200128);
        int*   curF   = (int*)(w + 200192);
        int*   listF  = (int*)(w + 200256);
        const int eblocks = (E_EDGES + 255) / 256;

        (void)hipMemsetAsync(out, 0, sizeof(float) * (size_t)N_NODES * COUT, stream);
        (void)hipMemsetAsync(degF, 0, sizeof(float) * (size_t)N_NODES, stream);
        (void)hipMemsetAsync(histF, 0, 192, stream);

        count_fb      <<<eblocks, 256, 0, stream>>>(ei, pseudo, histF, degF);
        scan16_fb     <<<1, 64, 0, stream>>>(histF, bstF, curF);
        scatter_fb    <<<eblocks, 256, 0, stream>>>(pseudo, curF, listF);
        bucket_mfma_fb<<<16 * 64, 256, 0, stream>>>(x, ei, pseudo, weight, listF,
                                                    bstF, histF, out);
        final_fb      <<<1024, 256, 0, stream>>>(x, root, bias, degF, out);
    }
}

// Round 8
// 160.899 us; speedup vs baseline: 1.1585x; 1.1585x over previous
//
#include <hip/hip_runtime.h>

#define N_NODES 50000
#define E_EDGES 800000
#define CIN     32
#define COUT    64
#define NB      16       // cell buckets
#define BCAP    54016    // per-bucket rec capacity (16-aligned; avg 50000 +18s)
#define NCB     196      // coarse row buckets (row>>8)
#define RCAP    4864     // per-coarse-bucket capacity (avg 4082 +12s)
#define BRT     1024     // build_recs block size (4x waves, SAME 391 blocks ->
                         // same 391-deep cursR atomic chains; R7's 1563-block
                         // variant quadrupled the chain depth: 43.5us, reverted)
#define EPB     2        // edges per thread in build_recs (BRT*EPB=2048/block)
#define BBLK    ((E_EDGES + EPB * BRT - 1) / (EPB * BRT))   // 391 blocks
#define XCHUNK  (N_NODES * CIN / 4)                // 400000 f4 chunks
#define KPAD    136      // fallback-path LDS row stride (shorts)

typedef __attribute__((ext_vector_type(8))) short s8v;   // 8 bf16 = 4 VGPRs
typedef __attribute__((ext_vector_type(4))) float f4v;
typedef __attribute__((ext_vector_type(4))) unsigned short u4v;

static __device__ inline unsigned short f2bf(float f) {  // RTNE via v_cvt_pk_bf16_f32
    __bf16 b = (__bf16)f;
    return __builtin_bit_cast(unsigned short, b);
}
static __device__ inline float bf2f(unsigned short h) {
    unsigned u = ((unsigned)h) << 16;
    return __builtin_bit_cast(float, u);
}
static __device__ inline unsigned f2bf2(float a, float b) {
    return (unsigned)f2bf(a) | ((unsigned)f2bf(b) << 16);
}

// ============ main path: zero scattered global atomics ============

// fused: x->bf16 slice + cell-bucketed recs + row-coarse (row,recslot) pairs.
// rec = row:16|col:16|f0q:16|f1q:16.  rp entry = recslot:20|rowlow:8.
__global__ __launch_bounds__(BRT) void build_recs(
    const float* __restrict__ x, unsigned short* __restrict__ xbf,
    const int* __restrict__ ei, const float* __restrict__ pseudo,
    int* __restrict__ cursor, int* __restrict__ cursR,
    unsigned long long* __restrict__ recs, unsigned* __restrict__ rp)
{
    // x2bf slice: 391 blocks x 1024 chunks covers 400384 >= 400000
    {
        const int i = blockIdx.x * BRT + threadIdx.x;
        if (i < XCHUNK) {
            f4v v = *(const f4v*)(x + (size_t)i * 4);
            union { unsigned u2[2]; u4v v4; } o;
            o.u2[0] = f2bf2(v[0], v[1]);
            o.u2[1] = f2bf2(v[2], v[3]);
            *(u4v*)(xbf + (size_t)i * 4) = o.v4;
        }
    }

    __shared__ int lh[NB];
    __shared__ int lbase[NB];
    __shared__ int lh2[NCB];
    __shared__ int lbase2[NCB];
    if (threadIdx.x < NB) lh[threadIdx.x] = 0;
    if (threadIdx.x < NCB) lh2[threadIdx.x] = 0;
    __syncthreads();

    const int ebase0 = blockIdx.x * (EPB * BRT);
    unsigned long long rcache[EPB];
    int pcache[EPB];    // b | myoff<<8
    int pcache2[EPB];   // cb | myoff2<<8

#pragma unroll
    for (int i = 0; i < EPB; ++i) {
        const int e = ebase0 + i * BRT + threadIdx.x;
        pcache[i] = -1; pcache2[i] = -1;
        if (e < E_EDGES) {
            const int row = min(max(ei[e], 0), N_NODES - 1);
            const int col = min(max(ei[E_EDGES + e], 0), N_NODES - 1);
            const float v0 = pseudo[2 * e] * 4.0f, v1 = pseudo[2 * e + 1] * 4.0f;
            const float fl0 = floorf(v0), fl1 = floorf(v1);
            const int lo0 = min(max((int)fl0, 0), 3);
            const int lo1 = min(max((int)fl1, 0), 3);
            const int f0q = min((int)((v0 - fl0) * 65536.0f), 65535);
            const int f1q = min((int)((v1 - fl1) * 65536.0f), 65535);
            const int b = lo0 + 4 * lo1;
            rcache[i] = (unsigned long long)row
                      | ((unsigned long long)col << 16)
                      | ((unsigned long long)f0q << 32)
                      | ((unsigned long long)f1q << 48);
            pcache[i]  = b | (atomicAdd(&lh[b], 1) << 8);
            const int cb = row >> 8;
            pcache2[i] = cb | (atomicAdd(&lh2[cb], 1) << 8);
        }
    }
    __syncthreads();

    if (threadIdx.x < NB)
        lbase[threadIdx.x] = atomicAdd(&cursor[threadIdx.x], lh[threadIdx.x]);
    if (threadIdx.x < NCB)
        lbase2[threadIdx.x] = atomicAdd(&cursR[threadIdx.x], lh2[threadIdx.x]);
    __syncthreads();

#pragma unroll
    for (int i = 0; i < EPB; ++i) {
        if (pcache[i] >= 0) {
            const int b = pcache[i] & 0xFF;
            const int idx = min(lbase[b] + (pcache[i] >> 8), BCAP - 1);
            const unsigned recslot = (unsigned)(b * BCAP + idx);
            recs[recslot] = rcache[i];
            const int cb = pcache2[i] & 0xFF;
            const int idx2 = min(lbase2[cb] + (pcache2[i] >> 8), RCAP - 1);
            const unsigned rowlow = (unsigned)(rcache[i] & 0xFF);
            rp[(size_t)cb * RCAP + idx2] = recslot | (rowlow << 20);
        }
    }
}

// fused per-coarse-bucket: self-compute 196-entry bstart prefix (tiny, L2),
// load rp bucket to LDS once, 256-bin hist, in-block exclusive scan ->
// rowstart, then rank-assign -> dpos.
__global__ __launch_bounds__(256) void bucket_rank(
    const unsigned* __restrict__ rp, const int* __restrict__ cursR,
    int* __restrict__ rowstart, int* __restrict__ dpos)
{
    __shared__ unsigned ent[RCAP];
    __shared__ int h[256];
    __shared__ int ws[4];
    __shared__ int wo[4];
    __shared__ int cur[256];
    __shared__ int sbase;
    const int cb = blockIdx.x, tid = threadIdx.x;
    const int lane = tid & 63, wid = tid >> 6;
    h[tid] = 0;

    // scan 1: exclusive prefix over the 196 coarse-bucket counts
    {
        const int v = (tid < NCB) ? min(cursR[tid], RCAP) : 0;
        int val = v;
#pragma unroll
        for (int off = 1; off < 64; off <<= 1) {
            int t = __shfl_up(val, off);
            if (lane >= off) val += t;
        }
        if (lane == 63) ws[wid] = val;
        __syncthreads();
        if (tid == 0) {
            int a = 0;
#pragma unroll
            for (int w = 0; w < 4; ++w) { wo[w] = a; a += ws[w]; }
        }
        __syncthreads();
        if (tid == cb) sbase = wo[wid] + val - v;      // this block's base
        if (cb == 0 && tid == 0) rowstart[N_NODES] = wo[3] + ws[3];
    }
    __syncthreads();   // sbase visible; h zero-init covered; wo/ws consumed

    const int cnt = min(cursR[cb], RCAP);
    const unsigned* bp = rp + (size_t)cb * RCAP;
    for (int i = tid; i < cnt; i += 256) {
        const unsigned e = bp[i];
        ent[i] = e;
        atomicAdd(&h[e >> 20], 1);
    }
    __syncthreads();

    // scan 2: exclusive scan of h[256] (ws/wo safely reused)
    const int v = h[tid];
    int val = v;
#pragma unroll
    for (int off = 1; off < 64; off <<= 1) {
        int t = __shfl_up(val, off);
        if (lane >= off) val += t;
    }
    if (lane == 63) ws[wid] = val;
    __syncthreads();
    if (tid == 0) {
        int a = 0;
#pragma unroll
        for (int w = 0; w < 4; ++w) { wo[w] = a; a += ws[w]; }
    }
    __syncthreads();

    const int rs = sbase + wo[wid] + (val - v);
    const int row = cb * 256 + tid;
    if (row < N_NODES) rowstart[row] = rs;
    cur[tid] = rs;
    __syncthreads();

    for (int i = tid; i < cnt; i += 256) {
        const unsigned e = ent[i];
        const int pos = min(atomicAdd(&cur[e >> 20], 1), E_EDGES - 1);
        dpos[e & 0xFFFFF] = pos;
    }
}

// pass D: per-cell MFMA, pipelined; msg SCATTER-stored at row-sorted pos.
// LDS chunk-rotated (bank-conflict-free); 1/deg folded into the gather.
// !! LAUNCH CONFIG IS CORRECTNESS-SENSITIVE (empirical, R3+R4 failures):
// !!   (256,4) + grid 16*256  -> FAILS (absmax 0.024 clean / 468 poisoned)
// !!   (256,2) + grid 16*128  -> PASSES (R2, 173.1us). Do not bump without
// !!   a hardened-barrier variant; suspect codegen at the 128-VGPR cap
// !!   interacting with the wave_barrier-only pipeline.
__global__ __launch_bounds__(256, 2) void bucket_mfma_seq(
    const unsigned short* __restrict__ xbf, const float* __restrict__ weight,
    const unsigned long long* __restrict__ recs,
    const int* __restrict__ cursor,
    const int* __restrict__ dpos, unsigned short* __restrict__ msg)
{
    __shared__ short XS[4][2048];   // 4KB/wave: staging 16 rows x 256B (rot16)

    const int lane = threadIdx.x & 63;
    const int wid  = threadIdx.x >> 6;
    const int cell = blockIdx.x & (NB - 1);
    const int wGlob   = (blockIdx.x >> 4) * 4 + wid;
    const int wStride = (gridDim.x >> 4) * 4;
    const int eg = lane >> 2, part = lane & 3;

    const int lo0 = cell & 3, lo1 = cell >> 2;
    const int base = lo0 + 5 * lo1;
    const int offs[4] = {0, 1, 5, 6};
    const int q = lane >> 4;
    const int c = lane & 15;

    s8v bfr[4][4];
#pragma unroll
    for (int s = 0; s < 4; ++s) {
        const float* wp = weight + (size_t)(base + offs[s]) * (CIN * COUT);
#pragma unroll
        for (int nt = 0; nt < 4; ++nt) {
            union { unsigned short u[8]; s8v v; } tmp;
#pragma unroll
            for (int j = 0; j < 8; ++j)
                tmp.u[j] = f2bf(wp[(q * 8 + j) * COUT + nt * 16 + c]);
            bfr[s][nt] = tmp.v;
        }
    }

    // loop-invariant rotated LDS addresses (shorts)
    short* const swrow = &XS[wid][eg * 128];           // staging write row
    int swoff[4];                                      // chunk (4s+part+eg)&15
#pragma unroll
    for (int s = 0; s < 4; ++s) swoff[s] = ((4 * s + part + eg) & 15) * 8;
    const short* const arrow = &XS[wid][c * 128];      // A-read row
    int aroff[4];                                      // chunk (4ks+q+c)&15
#pragma unroll
    for (int ks = 0; ks < 4; ++ks) aroff[ks] = ((4 * ks + q + c) & 15) * 8;
    // epilogue (rows of 128B = 8 chunks, rot8)
    const int erlo = eg * 64 + ((part + eg) & 7) * 8;        // read vlo
    const int erhi = eg * 64 + ((part + 4 + eg) & 7) * 8;    // read vhi

    const unsigned long long* brec = recs + (size_t)cell * BCAP;
    const int* bdp = dpos + (size_t)cell * BCAP;
    const int cnt    = min(cursor[cell], BCAP);
    const int ntiles = (cnt + 15) >> 4;

    int t = wGlob;
    unsigned long long rec_c = 0;
    int dp_c  = 0;
    s8v x_c = {};
    if (t < ntiles) {
        const int ri = min(t * 16 + eg, cnt - 1);
        rec_c = brec[ri];
        dp_c  = bdp[ri];
        x_c = *(const s8v*)(xbf + (size_t)((rec_c >> 16) & 0xFFFF) * CIN + part * 8);
    }

    for (; t < ntiles; t += wStride) {
        const int tn = t + wStride;
        unsigned long long rec_n = 0;
        int dp_n  = 0;
        if (tn < ntiles) {
            const int ri = min(tn * 16 + eg, cnt - 1);
            rec_n = brec[ri];
            dp_n  = bdp[ri];
        }

        const bool vcur = (t * 16 + eg) < cnt;
        const float f0 = (float)(int)((rec_c >> 32) & 0xFFFF) * (1.0f / 65536.0f);
        const float f1 = (float)(int)((rec_c >> 48) & 0xFFFF) * (1.0f / 65536.0f);
        const float s0 = (1.0f - f0) * (1.0f - f1);
        const float s1 = f0 * (1.0f - f1);
        const float s2 = (1.0f - f0) * f1;
        const float s3 = f0 * f1;

        // stage scaled X' (16 x 128 bf16), chunk-rotated
        {
            union { unsigned short u[8]; s8v v; } xin; xin.v = x_c;
            float xv[8];
#pragma unroll
            for (int j = 0; j < 8; ++j) xv[j] = bf2f(xin.u[j]);
            const float ss[4] = {s0, s1, s2, s3};
#pragma unroll
            for (int s = 0; s < 4; ++s) {
                union { unsigned u2[4]; s8v v; } tmp;
#pragma unroll
                for (int j = 0; j < 8; j += 2)
                    tmp.u2[j >> 1] = f2bf2(ss[s] * xv[j], ss[s] * xv[j + 1]);
                *(s8v*)(swrow + swoff[s]) = tmp.v;
            }
        }
        __builtin_amdgcn_wave_barrier();

        s8v afr[4];
#pragma unroll
        for (int ks = 0; ks < 4; ++ks)
            afr[ks] = *(const s8v*)(arrow + aroff[ks]);
        __builtin_amdgcn_wave_barrier();

        // next tile's x gather overlaps MFMA + epilogue
        s8v x_n = {};
        if (tn < ntiles)
            x_n = *(const s8v*)(xbf + (size_t)((rec_n >> 16) & 0xFFFF) * CIN + part * 8);

        f4v acc[4];
#pragma unroll
        for (int nt = 0; nt < 4; ++nt) {
            acc[nt] = (f4v){0.f, 0.f, 0.f, 0.f};
#pragma unroll
            for (int ks = 0; ks < 4; ++ks)
                acc[nt] = __builtin_amdgcn_mfma_f32_16x16x32_bf16(
                    afr[ks], bfr[ks][nt], acc[nt], 0, 0, 0);
        }

        // epilogue: acc -> bf16 tile in LDS (rot8) -> 128B scatter store at dp_c
#pragma unroll
        for (int r = 0; r < 4; ++r) {
            const int m = q * 4 + r;
#pragma unroll
            for (int nt = 0; nt < 4; ++nt) {
                const int chunk = (2 * nt + (c >> 3) + m) & 7;
                XS[wid][m * 64 + chunk * 8 + (c & 7)] = (short)f2bf(acc[nt][r]);
            }
        }
        __builtin_amdgcn_wave_barrier();
        if (vcur) {
            s8v vlo = *(const s8v*)&XS[wid][erlo];
            s8v vhi = *(const s8v*)&XS[wid][erhi];
            unsigned short* dst = msg + (size_t)dp_c * COUT + part * 8;
            *(s8v*)dst = vlo;
            *(s8v*)(dst + 32) = vhi;
        }
        __builtin_amdgcn_wave_barrier();

        rec_c = rec_n; dp_c = dp_n; x_c = x_n;
    }
}

// pass E: SEQUENTIAL per-node segment sum (msg already row-sorted) +
// 1/deg (deg == segment length) + root/bias fuse.
__global__ __launch_bounds__(256) void gather_seq(
    const unsigned short* __restrict__ msg,
    const int* __restrict__ rowstart, const float* __restrict__ x,
    const float* __restrict__ root, const float* __restrict__ bias,
    float* __restrict__ out)
{
    const int wave   = (blockIdx.x * blockDim.x + threadIdx.x) >> 6;
    const int lane   = threadIdx.x & 63;
    const int nwaves = (gridDim.x * blockDim.x) >> 6;
    const int g = lane >> 3;   // 0..7: position group / root i-range
    const int c = lane & 7;    // channel octet: channels c*8 .. c*8+7

    // hoist root fragment (this lane's 4 rows x 8 channels) + bias
    float rfr[4][8];
#pragma unroll
    for (int i = 0; i < 4; ++i) {
        const int ii = g * 4 + i;
        *(f4v*)&rfr[i][0] = *(const f4v*)(root + (size_t)ii * COUT + c * 8);
        *(f4v*)&rfr[i][4] = *(const f4v*)(root + (size_t)ii * COUT + c * 8 + 4);
    }
    float bs[8];
    *(f4v*)&bs[0] = *(const f4v*)(bias + c * 8);
    *(f4v*)&bs[4] = *(const f4v*)(bias + c * 8 + 4);

    for (int n = wave; n < N_NODES; n += nwaves) {
        const int s  = rowstart[n];
        const int e2 = rowstart[n + 1];
        float acc[8] = {0.f, 0.f, 0.f, 0.f, 0.f, 0.f, 0.f, 0.f};

        // streaming segment sum: 8 positions x 64 ch per wave iteration
        for (int p = s + g; p < e2; p += 8) {
            union { s8v v; unsigned short u[8]; } mv;
            mv.v = *(const s8v*)(msg + (size_t)p * COUT + c * 8);
#pragma unroll
            for (int j = 0; j < 8; ++j)
                acc[j] += bf2f(mv.u[j]);
        }

        // 1/deg scaling (deg == segment length; applied before root partial)
        const float invd = 1.0f / (float)max(e2 - s, 1);
#pragma unroll
        for (int j = 0; j < 8; ++j) acc[j] *= invd;

        // root partial: this group's 4 input channels
        const f4v xv4 = *(const f4v*)(x + (size_t)n * CIN + g * 4);
#pragma unroll
        for (int i = 0; i < 4; ++i) {
            const float xv = xv4[i];
#pragma unroll
            for (int j = 0; j < 8; ++j)
                acc[j] += xv * rfr[i][j];
        }

        // reduce across the 8 groups
#pragma unroll
        for (int off = 8; off < 64; off <<= 1) {
#pragma unroll
            for (int j = 0; j < 8; ++j)
                acc[j] += __shfl_xor(acc[j], off);
        }

        if (g == 0) {
            f4v o0, o1;
#pragma unroll
            for (int j = 0; j < 4; ++j) o0[j] = acc[j] + bs[j];
#pragma unroll
            for (int j = 0; j < 4; ++j) o1[j] = acc[4 + j] + bs[4 + j];
            float* op = out + (size_t)n * COUT + c * 8;
            *(f4v*)op = o0;
            *(f4v*)(op + 4) = o1;
        }
    }
}

// ================= fallback (R4 atomic) path =================

__global__ __launch_bounds__(256) void count_fb(
    const int* __restrict__ ei, const float* __restrict__ pseudo,
    int* __restrict__ hist, float* __restrict__ deg)
{
    __shared__ int lh[16];
    if (threadIdx.x < 16) lh[threadIdx.x] = 0;
    __syncthreads();
    const int e = blockIdx.x * 256 + threadIdx.x;
    if (e < E_EDGES) {
        int row = min(max(ei[e], 0), N_NODES - 1);
        const float v0 = pseudo[2 * e] * 4.0f, v1 = pseudo[2 * e + 1] * 4.0f;
        const int lo0 = min(max((int)floorf(v0), 0), 3);
        const int lo1 = min(max((int)floorf(v1), 0), 3);
        atomicAdd(&lh[lo0 + 4 * lo1], 1);
        atomicAdd(&deg[row], 1.0f);
    }
    __syncthreads();
    if (threadIdx.x < 16) atomicAdd(&hist[threadIdx.x], lh[threadIdx.x]);
}

__global__ void scan16_fb(const int* __restrict__ hist,
                          int* __restrict__ bstart, int* __restrict__ cursor)
{
    if (threadIdx.x == 0 && blockIdx.x == 0) {
        int acc = 0;
        for (int c = 0; c < 16; ++c) { bstart[c] = acc; cursor[c] = acc; acc += hist[c]; }
    }
}

__global__ __launch_bounds__(256) void scatter_fb(
    const float* __restrict__ pseudo, int* __restrict__ cursor, int* __restrict__ list)
{
    __shared__ int lh[16];
    __shared__ int lbase[16];
    if (threadIdx.x < 16) lh[threadIdx.x] = 0;
    __syncthreads();
    const int e = blockIdx.x * 256 + threadIdx.x;
    int cell = 0, myoff = 0;
    if (e < E_EDGES) {
        const float v0 = pseudo[2 * e] * 4.0f, v1 = pseudo[2 * e + 1] * 4.0f;
        const int lo0 = min(max((int)floorf(v0), 0), 3);
        const int lo1 = min(max((int)floorf(v1), 0), 3);
        cell = lo0 + 4 * lo1;
        myoff = atomicAdd(&lh[cell], 1);
    }
    __syncthreads();
    if (threadIdx.x < 16)
        lbase[threadIdx.x] = atomicAdd(&cursor[threadIdx.x], lh[threadIdx.x]);
    __syncthreads();
    if (e < E_EDGES)
        list[lbase[cell] + myoff] = e;
}

__global__ __launch_bounds__(256, 2) void bucket_mfma_fb(
    const float* __restrict__ x, const int* __restrict__ ei,
    const float* __restrict__ pseudo, const float* __restrict__ weight,
    const int* __restrict__ list, const int* __restrict__ bstart,
    const int* __restrict__ hist, float* __restrict__ out)
{
    __shared__ short XS[4][16 * KPAD];
    const int lane = threadIdx.x & 63;
    const int wid  = threadIdx.x >> 6;
    const int beta = blockIdx.x & 15;
    const int wGlob   = (blockIdx.x >> 4) * 4 + wid;
    const int wStride = (gridDim.x >> 4) * 4;
    const int lo0 = beta & 3, lo1 = beta >> 2;
    const int base = lo0 + 5 * lo1;
    const int offs[4] = {0, 1, 5, 6};
    const int q = lane >> 4, c = lane & 15;

    s8v bfr[4][4];
#pragma unroll
    for (int s = 0; s < 4; ++s) {
        const float* wp = weight + (size_t)(base + offs[s]) * (CIN * COUT);
#pragma unroll
        for (int nt = 0; nt < 4; ++nt) {
            union { unsigned short u[8]; s8v v; } tmp;
#pragma unroll
            for (int j = 0; j < 8; ++j)
                tmp.u[j] = f2bf(wp[(q * 8 + j) * COUT + nt * 16 + c]);
            bfr[s][nt] = tmp.v;
        }
    }
    const int start = bstart[beta], cnt = hist[beta];
    const int ntiles = (cnt + 15) >> 4;

    for (int t = wGlob; t < ntiles; t += wStride) {
        const int ebase = start + t * 16;
        int rowv = 0, colv = 0;
        float b0 = 0.f, b1 = 0.f, b2 = 0.f, b3 = 0.f;
        if (lane < 16 && (t * 16 + lane) < cnt) {
            const int e = list[ebase + lane];
            rowv = min(max(ei[e], 0), N_NODES - 1);
            colv = min(max(ei[E_EDGES + e], 0), N_NODES - 1);
            const float v0 = pseudo[2 * e] * 4.0f, v1 = pseudo[2 * e + 1] * 4.0f;
            const float f0 = v0 - floorf(v0), f1 = v1 - floorf(v1);
            b0 = (1.0f - f0) * (1.0f - f1);
            b1 = f0 * (1.0f - f1);
            b2 = (1.0f - f0) * f1;
            b3 = f0 * f1;
        }
        {
            const int eg = lane >> 2, part = lane & 3;
            const int  gc = __shfl(colv, eg);
            const float ss0 = __shfl(b0, eg), ss1 = __shfl(b1, eg);
            const float ss2 = __shfl(b2, eg), ss3 = __shfl(b3, eg);
            const float ss[4] = {ss0, ss1, ss2, ss3};
            const float* xp = x + (size_t)gc * CIN + part * 8;
            float xv[8];
            *(f4v*)&xv[0] = *(const f4v*)xp;
            *(f4v*)&xv[4] = *(const f4v*)(xp + 4);
            short* dst = &XS[wid][eg * KPAD + part * 8];
#pragma unroll
            for (int s = 0; s < 4; ++s) {
                union { unsigned short u[8]; s8v v; } tmp;
#pragma unroll
                for (int j = 0; j < 8; ++j)
                    tmp.u[j] = f2bf(ss[s] * xv[j]);
                *(s8v*)(dst + s * 32) = tmp.v;
            }
        }
        __builtin_amdgcn_wave_barrier();
        s8v afr[4];
        {
            const short* ap = &XS[wid][c * KPAD + q * 8];
#pragma unroll
            for (int ks = 0; ks < 4; ++ks)
                afr[ks] = *(const s8v*)(ap + ks * 32);
        }
        __builtin_amdgcn_wave_barrier();
        f4v acc[4];
#pragma unroll
        for (int nt = 0; nt < 4; ++nt) {
            acc[nt] = (f4v){0.f, 0.f, 0.f, 0.f};
#pragma unroll
            for (int ks = 0; ks < 4; ++ks)
                acc[nt] = __builtin_amdgcn_mfma_f32_16x16x32_bf16(
                    afr[ks], bfr[ks][nt], acc[nt], 0, 0, 0);
        }
#pragma unroll
        for (int r = 0; r < 4; ++r) {
            const int m = q * 4 + r;
            const int orow = __shfl(rowv, m);
#pragma unroll
            for (int nt = 0; nt < 4; ++nt)
                atomicAdd(&out[(size_t)orow * COUT + nt * 16 + c], acc[nt][r]);
        }
    }
}

__global__ __launch_bounds__(256) void final_fb(
    const float* __restrict__ x, const float* __restrict__ root,
    const float* __restrict__ bias, const float* __restrict__ deg,
    float* __restrict__ out)
{
    const int wave   = (blockIdx.x * blockDim.x + threadIdx.x) >> 6;
    const int lane   = threadIdx.x & 63;
    const int nwaves = (gridDim.x * blockDim.x) >> 6;
    for (int n = wave; n < N_NODES; n += nwaves) {
        const float* xp = x + (size_t)n * CIN;
        float acc = bias[lane];
#pragma unroll
        for (int i = 0; i < CIN; ++i)
            acc += xp[i] * root[i * COUT + lane];
        float dg = deg[n];
        dg = dg > 1.0f ? dg : 1.0f;
        const size_t idx = (size_t)n * COUT + lane;
        out[idx] = out[idx] / dg + acc;
    }
}

extern "C" void kernel_launch(void* const* d_in, const int* in_sizes, int n_in,
                              void* d_out, int out_size, void* d_ws, size_t ws_size,
                              hipStream_t stream) {
    const float* x      = (const float*)d_in[0];
    const int*   ei     = (const int*)d_in[1];
    const float* pseudo = (const float*)d_in[2];
    const float* weight = (const float*)d_in[3];
    const float* root   = (const float*)d_in[4];
    const float* bias   = (const float*)d_in[5];
    float* out = (float*)d_out;

    // ws layout (int elements)
    int* wsI = (int*)d_ws;
    int* cursor16 = wsI;                         // 16 (+16 pad)
    int* cursR    = wsI + 32;                    // 196 (+28 pad) -> 224
    int* rowstart = wsI + 50256;                 // 50001 (+15 pad)
    // byte offsets from 100352*4 = 401408 (layout kept from prev rounds)
    unsigned long long* recs = (unsigned long long*)((char*)d_ws + 401408);        // 6.91 MB
    unsigned* rp   = (unsigned*)((char*)recs + (size_t)NB * BCAP * 8);             // 3.81 MB
    int* dpos      = (int*)((char*)rp + (size_t)NCB * RCAP * 4);                   // 3.46 MB
    unsigned short* xbf = (unsigned short*)((char*)dpos + (size_t)NB * BCAP * 4);  // 3.2 MB
    unsigned short* msg = (unsigned short*)((char*)xbf + (size_t)N_NODES * CIN * 2); // 102.4 MB
    const size_t needed = 401408 + (size_t)NB * BCAP * 8 + (size_t)NCB * RCAP * 4
                        + (size_t)NB * BCAP * 4 + (size_t)N_NODES * CIN * 2
                        + (size_t)E_EDGES * COUT * 2;   // ~120.2 MB

    if (ws_size >= needed) {
        (void)hipMemsetAsync(d_ws, 0, 256 * 4, stream);   // cursor16 + cursR only
        build_recs <<<BBLK, BRT, 0, stream>>>(x, xbf, ei, pseudo, cursor16, cursR, recs, rp);
        bucket_rank<<<NCB, 256, 0, stream>>>(rp, cursR, rowstart, dpos);
        bucket_mfma_seq<<<16 * 128, 256, 0, stream>>>(
            xbf, weight, recs, cursor16, dpos, msg);
        gather_seq<<<4096, 256, 0, stream>>>(msg, rowstart, x, root, bias, out);
    } else {
        // R4 fallback layout
        char* w = (char*)d_ws;
        float* degF   = (float*)w;
        int*   histF  = (int*)(w + 200064);
        int*   bstF   = (int*)(w + 200128);
        int*   curF   = (int*)(w + 200192);
        int*   listF  = (int*)(w + 200256);
        const int eblocks = (E_EDGES + 255) / 256;

        (void)hipMemsetAsync(out, 0, sizeof(float) * (size_t)N_NODES * COUT, stream);
        (void)hipMemsetAsync(degF, 0, sizeof(float) * (size_t)N_NODES, stream);
        (void)hipMemsetAsync(histF, 0, 192, stream);

        count_fb      <<<eblocks, 256, 0, stream>>>(ei, pseudo, histF, degF);
        scan16_fb     <<<1, 64, 0, stream>>>(histF, bstF, curF);
        scatter_fb    <<<eblocks, 256, 0, stream>>>(pseudo, curF, listF);
        bucket_mfma_fb<<<16 * 64, 256, 0, stream>>>(x, ei, pseudo, weight, listF,
                                                    bstF, histF, out);
        final_fb      <<<1024, 256, 0, stream>>>(x, root, bias, degF, out);
    }
}